// Round 7
// baseline (153.006 us; speedup 1.0000x reference)
//
#include <hip/hip_runtime.h>
#include <hip/hip_bf16.h>
#include <math.h>
#include <stdint.h>

// Problem constants
#define T_ROWS 16384
#define D_DIM  4096
#define E_EXP  64
#define TOPK   8

constexpr float W_SCALE   = 64.0f;     // folded into Whi/Wlo by wprep
constexpr float INV_SCALE = 1.0f / 64.0f;

constexpr int BM   = 32;               // rows per block
constexpr int BK   = 64;               // k per step
constexpr int NIT  = D_DIM / BK;       // 64
constexpr int ABUF = 8192;             // 32 rows x 64 f32 (16 x 16B chunks/row)
constexpr int LDS_TOT = 3 * ABUF;      // 24576 (triple-buffered A only)

typedef _Float16 f16x8 __attribute__((ext_vector_type(8)));
typedef __fp16   h16x2 __attribute__((ext_vector_type(2)));
typedef float    f32x4 __attribute__((ext_vector_type(4)));

__device__ __forceinline__ void gll16(const void* g, void* l) {
    __builtin_amdgcn_global_load_lds(
        (const __attribute__((address_space(1))) void*)g,
        (__attribute__((address_space(3))) void*)l, 16, 0, 0);
}
#define WAITV(n) asm volatile("s_waitcnt vmcnt(" #n ")" ::: "memory")

// ---------------------------------------------------------------------------
// K0: W (f32 [64][4096]) -> linear hi/lo f16 [64][4096], scaled by 64.
// ---------------------------------------------------------------------------
__global__ __launch_bounds__(256) void wprep_kernel(
    const float* __restrict__ W, _Float16* __restrict__ Whi,
    _Float16* __restrict__ Wlo)
{
    const int i = blockIdx.x * 256 + threadIdx.x;     // 32768 threads, 8 k each
    const int k = i << 3;
    const float4 w0 = *(const float4*)&W[(size_t)k];
    const float4 w1 = *(const float4*)&W[(size_t)k + 4];
    const float xs[8] = {w0.x, w0.y, w0.z, w0.w, w1.x, w1.y, w1.z, w1.w};
    f16x8 hi, lo;
    #pragma unroll
    for (int j = 0; j < 8; ++j) {
        const float x = xs[j] * W_SCALE;
        const _Float16 hh = (_Float16)x;
        hi[j] = hh;
        lo[j] = (_Float16)(x - (float)hh);
    }
    *(f16x8*)(Whi + k) = hi;
    *(f16x8*)(Wlo + k) = lo;
}

// exact split of f32 into (f16-exact hi via mantissa mask) + lo, packed cvt
__device__ __forceinline__ void cvt8(const float4 x0, const float4 x1,
                                     f16x8& hi, f16x8& lo) {
    const float xs[8] = {x0.x, x0.y, x0.z, x0.w, x1.x, x1.y, x1.z, x1.w};
    float hs[8], ls[8];
    #pragma unroll
    for (int j = 0; j < 8; ++j) {
        hs[j] = __uint_as_float(__float_as_uint(xs[j]) & 0xFFFFE000u);
        ls[j] = xs[j] - hs[j];
    }
    #pragma unroll
    for (int j = 0; j < 4; ++j) {
        const h16x2 ph = __builtin_amdgcn_cvt_pkrtz(hs[2 * j], hs[2 * j + 1]);
        const h16x2 pl = __builtin_amdgcn_cvt_pkrtz(ls[2 * j], ls[2 * j + 1]);
        hi[2 * j] = (_Float16)ph[0]; hi[2 * j + 1] = (_Float16)ph[1];
        lo[2 * j] = (_Float16)pl[0]; lo[2 * j + 1] = (_Float16)pl[1];
    }
}

// ---------------------------------------------------------------------------
// K1: fused router. A: global->LDS (triple-buffer, counted vmcnt).
//     B: L2-resident Whi/Wlo direct global->reg, 1-iter ping-pong.
// 512 blocks x 256 thr (4 waves); wave (wm,we) = rows wm*16..+16 x experts
// we*32..+32.
// ---------------------------------------------------------------------------
__global__ __launch_bounds__(256, 3) void router_main_kernel(
    const float* __restrict__ h, const _Float16* __restrict__ Whi,
    const _Float16* __restrict__ Wlo, const float* __restrict__ u,
    float* __restrict__ out)
{
    __shared__ union {
        char raw[LDS_TOT];
        float logits[BM][E_EXP + 4];
    } sm;
    char* smb = sm.raw;

    const int tid  = threadIdx.x;
    const int wv   = tid >> 6;
    const int lane = tid & 63;
    const int l15  = lane & 15;
    const int kg   = lane >> 4;          // 0..3
    const int wm   = wv >> 1;            // m-half
    const int we   = wv & 1;             // e-half
    const int row0 = blockIdx.x * BM;

    // ---- A staging: wave stages rows wv*8..+7; lane: row 4j+kg, chunk l15.
    // Pre-swizzled global source (chunk l15 ^ (row&7)); LDS dest linear.
    const char* gA[2]; int lA[2];
    #pragma unroll
    for (int p = 0; p < 2; ++p) {
        const int j   = wv * 2 + p;
        const int row = j * 4 + kg;
        gA[p] = (const char*)h + (size_t)(row0 + row) * (D_DIM * 4)
                + ((l15 ^ (row & 7)) << 4);
        lA[p] = j * 1024;
    }

    // ---- A ds_read byte offsets (within one buffer) ----
    int aro[2][2];                       // [kc][piece]
    {
        const int row = wm * 16 + l15, s7 = l15 & 7;
        #pragma unroll
        for (int kc = 0; kc < 2; ++kc)
            #pragma unroll
            for (int q2 = 0; q2 < 2; ++q2)
                aro[kc][q2] = row * 256 + (((kc * 8 + kg * 2 + q2) ^ s7) << 4);
    }

    // ---- B pointers: lane covers expert e = we*32+es*16+l15, k-octet kg ----
    const _Float16* bph[2]; const _Float16* bpl[2];
    #pragma unroll
    for (int es = 0; es < 2; ++es) {
        const size_t off = (size_t)(we * 32 + es * 16 + l15) * D_DIM + kg * 8;
        bph[es] = Whi + off;
        bpl[es] = Wlo + off;
    }

    f32x4 acc[2] = {};                   // [es]
    f16x8 b0h[2][2], b0l[2][2], b1h[2][2], b1l[2][2];   // [es][kc]

    int aCur = 0, aNxt = ABUF, aStg = 2 * ABUF;

    #define STAGE_A(t, aAdd)                                          \
        { _Pragma("unroll")                                           \
          for (int p = 0; p < 2; ++p)                                 \
              gll16(gA[p] + (size_t)(t) * 256, smb + (aAdd) + lA[p]); }

    #define LOADB(t, R)                                               \
        { _Pragma("unroll")                                           \
          for (int es = 0; es < 2; ++es)                              \
              _Pragma("unroll")                                       \
              for (int kc = 0; kc < 2; ++kc) {                        \
                  R##h[es][kc] = *(const f16x8*)(bph[es] + (t) * 64 + kc * 32); \
                  R##l[es][kc] = *(const f16x8*)(bpl[es] + (t) * 64 + kc * 32); \
              } }

    #define COMPUTE(aAdd, R)                                                  \
        { float4 av[2][2];                                                    \
          _Pragma("unroll")                                                   \
          for (int kc = 0; kc < 2; ++kc)                                      \
              _Pragma("unroll")                                               \
              for (int q2 = 0; q2 < 2; ++q2)                                  \
                  av[kc][q2] = *(const float4*)(smb + (aAdd) + aro[kc][q2]);  \
          f16x8 ah[2], al[2];                                                 \
          cvt8(av[0][0], av[0][1], ah[0], al[0]);                             \
          cvt8(av[1][0], av[1][1], ah[1], al[1]);                             \
          _Pragma("unroll")                                                   \
          for (int es = 0; es < 2; ++es)                                      \
              _Pragma("unroll")                                               \
              for (int kc = 0; kc < 2; ++kc) {                                \
                  acc[es] = __builtin_amdgcn_mfma_f32_16x16x32_f16(ah[kc], R##h[es][kc], acc[es], 0, 0, 0); \
                  acc[es] = __builtin_amdgcn_mfma_f32_16x16x32_f16(ah[kc], R##l[es][kc], acc[es], 0, 0, 0); \
                  acc[es] = __builtin_amdgcn_mfma_f32_16x16x32_f16(al[kc], R##h[es][kc], acc[es], 0, 0, 0); \
              } }

    #define ROT() { int t = aCur; aCur = aNxt; aNxt = aStg; aStg = t; }

    // prologue: A(0), A(1) staged; B(0) in regs
    STAGE_A(0, aCur)
    STAGE_A(1, aNxt)
    LOADB(0, b0)
    WAITV(10);                           // A(0)'s 2 gll landed
    __builtin_amdgcn_s_barrier();

    // main loop: 62 k-steps, 2-deep A pipeline, 1-deep B reg ping-pong.
    // per iter: 2 gll + 8 B-loads issued; WAITV(10) keeps them in flight.
    for (int i = 0; i < NIT - 2; i += 2) {
        STAGE_A(i + 2, aStg)
        LOADB(i + 1, b1)
        COMPUTE(aCur, b0)
        WAITV(10);
        __builtin_amdgcn_s_barrier();
        ROT();
        STAGE_A(i + 3, aStg)
        LOADB(i + 2, b0)
        COMPUTE(aCur, b1)
        WAITV(10);
        __builtin_amdgcn_s_barrier();
        ROT();
    }
    // tail: k-steps 62, 63
    LOADB(NIT - 1, b1)
    COMPUTE(aCur, b0)
    WAITV(8);                            // A(63) drained; B(63) in flight
    __builtin_amdgcn_s_barrier();
    ROT();
    COMPUTE(aCur, b1)
    __builtin_amdgcn_s_barrier();        // all LDS reads done -> safe to alias

    // ---- fused epilogue ----
    #pragma unroll
    for (int es = 0; es < 2; ++es)
        #pragma unroll
        for (int r = 0; r < 4; ++r)
            sm.logits[wm * 16 + kg * 4 + r][we * 32 + es * 16 + l15]
                = acc[es][r] * INV_SCALE;
    __syncthreads();

    const size_t te = (size_t)T_ROWS * E_EXP;
    #pragma unroll
    for (int rr = 0; rr < 8; ++rr) {
        const int rl = wv * 8 + rr;
        const int gr = row0 + rl;
        const size_t idx = (size_t)gr * E_EXP + lane;
        const float val = sm.logits[rl][lane];

        out[2 * te + idx] = val;                      // logits_clean

        float m = val;
        #pragma unroll
        for (int off = 32; off; off >>= 1) m = fmaxf(m, __shfl_xor(m, off));
        const float p = expf(val - m);
        float ssum = p;
        #pragma unroll
        for (int off = 32; off; off >>= 1) ssum += __shfl_xor(ssum, off);
        out[1 * te + idx] = p / ssum;                 // probs

        const float uv = u[idx];
        const float g = -logf(-logf(uv));
        const float sel = val + g;
        out[3 * te + idx] = sel;                      // logits_sel

        // top-8, ties -> lowest lane (= lowest expert, matches lax.top_k)
        float v = sel;
        bool chosen = false;
        #pragma unroll
        for (int itk = 0; itk < TOPK; ++itk) {
            float mv = v;
            #pragma unroll
            for (int off = 32; off; off >>= 1) mv = fmaxf(mv, __shfl_xor(mv, off));
            const unsigned long long b = __ballot(v == mv);
            const int sl = __ffsll((long long)b) - 1;
            if (lane == sl) { chosen = true; v = -INFINITY; }
        }
        out[idx] = chosen ? 1.0f : 0.0f;              // mask
    }
}

// ---------------------------------------------------------------------------
extern "C" void kernel_launch(void* const* d_in, const int* in_sizes, int n_in,
                              void* d_out, int out_size, void* d_ws, size_t ws_size,
                              hipStream_t stream) {
    const float* h = (const float*)d_in[0];
    const float* W = (const float*)d_in[1];
    const float* u = (const float*)d_in[2];
    float* out = (float*)d_out;

    _Float16* Whi = (_Float16*)d_ws;                       // 512 KB
    _Float16* Wlo = Whi + (size_t)E_EXP * D_DIM;           // 512 KB

    hipLaunchKernelGGL(wprep_kernel, dim3(E_EXP * D_DIM / 8 / 256), dim3(256),
                       0, stream, W, Whi, Wlo);
    hipLaunchKernelGGL(router_main_kernel, dim3(T_ROWS / BM), dim3(256),
                       0, stream, h, Whi, Wlo, u, out);
}

// Round 8
// 151.119 us; speedup vs baseline: 1.0125x; 1.0125x over previous
//
#include <hip/hip_runtime.h>
#include <hip/hip_bf16.h>
#include <math.h>
#include <stdint.h>

// Problem constants
#define T_ROWS 16384
#define D_DIM  4096
#define E_EXP  64
#define TOPK   8

constexpr float W_SCALE   = 64.0f;     // folded into Whi/Wlo by wprep
constexpr float INV_SCALE = 1.0f / 64.0f;

constexpr int BM   = 32;               // rows per block
constexpr int BK   = 64;               // k per step
constexpr int NIT  = D_DIM / BK;       // 64
constexpr int ABUF = 8192;             // 32 rows x 16 chunks x 16B
constexpr int LDS_TOT = 3 * ABUF;      // 24576 (triple-buffered A)

typedef _Float16     f16x8  __attribute__((ext_vector_type(8)));
typedef __fp16       h16x2  __attribute__((ext_vector_type(2)));
typedef float        f32x4  __attribute__((ext_vector_type(4)));
typedef unsigned int ui32x4 __attribute__((ext_vector_type(4)));

__device__ __forceinline__ void gll16(const void* g, void* l) {
    __builtin_amdgcn_global_load_lds(
        (const __attribute__((address_space(1))) void*)g,
        (__attribute__((address_space(3))) void*)l, 16, 0, 0);
}
#define WAITV(n) asm volatile("s_waitcnt vmcnt(" #n ")" ::: "memory")
#define SB0()    __builtin_amdgcn_sched_barrier(0)

// ---------------------------------------------------------------------------
// K0: W (f32 [64][4096]) -> linear hi/lo f16 [64][4096], scaled by 64.
// ---------------------------------------------------------------------------
__global__ __launch_bounds__(256) void wprep_kernel(
    const float* __restrict__ W, _Float16* __restrict__ Whi,
    _Float16* __restrict__ Wlo)
{
    const int i = blockIdx.x * 256 + threadIdx.x;     // 32768 threads, 8 k each
    const int k = i << 3;
    const float4 w0 = *(const float4*)&W[(size_t)k];
    const float4 w1 = *(const float4*)&W[(size_t)k + 4];
    const float xs[8] = {w0.x, w0.y, w0.z, w0.w, w1.x, w1.y, w1.z, w1.w};
    f16x8 hi, lo;
    #pragma unroll
    for (int j = 0; j < 8; ++j) {
        const float x = xs[j] * W_SCALE;
        const _Float16 hh = (_Float16)x;
        hi[j] = hh;
        lo[j] = (_Float16)(x - (float)hh);
    }
    *(f16x8*)(Whi + k) = hi;
    *(f16x8*)(Wlo + k) = lo;
}

// exact split of f32 into (f16-exact hi via mantissa mask) + lo, packed cvt
__device__ __forceinline__ void cvt8(const float4 x0, const float4 x1,
                                     f16x8& hi, f16x8& lo) {
    const float xs[8] = {x0.x, x0.y, x0.z, x0.w, x1.x, x1.y, x1.z, x1.w};
    float hs[8], ls[8];
    #pragma unroll
    for (int j = 0; j < 8; ++j) {
        hs[j] = __uint_as_float(__float_as_uint(xs[j]) & 0xFFFFE000u);
        ls[j] = xs[j] - hs[j];
    }
    #pragma unroll
    for (int j = 0; j < 4; ++j) {
        const h16x2 ph = __builtin_amdgcn_cvt_pkrtz(hs[2 * j], hs[2 * j + 1]);
        const h16x2 pl = __builtin_amdgcn_cvt_pkrtz(ls[2 * j], ls[2 * j + 1]);
        hi[2 * j] = (_Float16)ph[0]; hi[2 * j + 1] = (_Float16)ph[1];
        lo[2 * j] = (_Float16)pl[0]; lo[2 * j + 1] = (_Float16)pl[1];
    }
}

// ---------------------------------------------------------------------------
// K1: fused router. A: global->LDS via gll (triple-buffer, counted vmcnt,
//     c^(r&15) chunk swizzle). B: L2-resident Whi/Wlo via inline-asm
//     global_load_dwordx4 into pinned regs, 2-iter-ahead ping-pong.
// 512 blocks x 256 thr; wave (wm,we) = rows wm*16..+16 x experts we*32..+32.
// ---------------------------------------------------------------------------
__global__ __launch_bounds__(256, 3) void router_main_kernel(
    const float* __restrict__ h, const _Float16* __restrict__ Whi,
    const _Float16* __restrict__ Wlo, const float* __restrict__ u,
    float* __restrict__ out)
{
    __shared__ union {
        char raw[LDS_TOT];
        float logits[BM][E_EXP + 4];
    } sm;
    char* smb = sm.raw;

    const int tid  = threadIdx.x;
    const int wv   = tid >> 6;
    const int lane = tid & 63;
    const int l15  = lane & 15;
    const int kg   = lane >> 4;          // 0..3
    const int wm   = wv >> 1;            // m-half
    const int we   = wv & 1;             // e-half
    const int row0 = blockIdx.x * BM;

    // ---- A staging: wave stages rows wv*8..+7; lane: row 4j+kg, LDS chunk l15.
    // Content at (row, c') = global chunk c' ^ (row&15); LDS dest linear.
    const char* gA[2]; int lA[2];
    #pragma unroll
    for (int p = 0; p < 2; ++p) {
        const int j   = wv * 2 + p;
        const int row = j * 4 + kg;
        gA[p] = (const char*)h + (size_t)(row0 + row) * (D_DIM * 4)
                + ((l15 ^ (row & 15)) << 4);
        lA[p] = j * 1024;
    }

    // ---- A ds_read byte offsets: row R=wm*16+l15 (R&15=l15), chunk c^(l15) ----
    int aro[2][2];                       // [kc][piece]
    #pragma unroll
    for (int kc = 0; kc < 2; ++kc)
        #pragma unroll
        for (int q2 = 0; q2 < 2; ++q2)
            aro[kc][q2] = (wm * 16 + l15) * 256
                        + (((kc * 8 + kg * 2 + q2) ^ l15) << 4);

    // ---- B pointers: lane covers expert e = we*32+es*16+l15, k-octet kg ----
    const char* bph[2]; const char* bpl[2];
    #pragma unroll
    for (int es = 0; es < 2; ++es) {
        const size_t off = ((size_t)(we * 32 + es * 16 + l15) * D_DIM + kg * 8) * 2;
        bph[es] = (const char*)Whi + off;
        bpl[es] = (const char*)Wlo + off;
    }

    f32x4 acc[2] = {};                    // [es]
    ui32x4 b0h[2][2], b0l[2][2], b1h[2][2], b1l[2][2];   // [es][kc]

    int aCur = 0, aNxt = ABUF, aStg = 2 * ABUF;

    #define STAGE_A(t, aAdd)                                          \
        { _Pragma("unroll")                                           \
          for (int p = 0; p < 2; ++p)                                 \
              gll16(gA[p] + (size_t)(t) * 256, smb + (aAdd) + lA[p]); }

    // inline-asm B loads: cannot be sunk/collapsed by the compiler.
    #define LOADB(t, R)                                                        \
        { _Pragma("unroll")                                                    \
          for (int es = 0; es < 2; ++es)                                       \
              _Pragma("unroll")                                                \
              for (int kc = 0; kc < 2; ++kc) {                                 \
                  const char* ph_ = bph[es] + (size_t)(t) * 128 + kc * 64;     \
                  const char* pl_ = bpl[es] + (size_t)(t) * 128 + kc * 64;     \
                  asm volatile("global_load_dwordx4 %0, %1, off"               \
                               : "=v"(R##h[es][kc]) : "v"(ph_));               \
                  asm volatile("global_load_dwordx4 %0, %1, off"               \
                               : "=v"(R##l[es][kc]) : "v"(pl_));               \
              } }

    #define COMPUTE(aAdd, R)                                                   \
        { float4 av[2][2];                                                     \
          _Pragma("unroll")                                                    \
          for (int kc = 0; kc < 2; ++kc)                                       \
              _Pragma("unroll")                                                \
              for (int q2 = 0; q2 < 2; ++q2)                                   \
                  av[kc][q2] = *(const float4*)(smb + (aAdd) + aro[kc][q2]);   \
          f16x8 ah[2], al[2];                                                  \
          cvt8(av[0][0], av[0][1], ah[0], al[0]);                              \
          cvt8(av[1][0], av[1][1], ah[1], al[1]);                              \
          _Pragma("unroll")                                                    \
          for (int es = 0; es < 2; ++es)                                       \
              _Pragma("unroll")                                                \
              for (int kc = 0; kc < 2; ++kc) {                                 \
                  const f16x8 bh_ = __builtin_bit_cast(f16x8, R##h[es][kc]);   \
                  const f16x8 bl_ = __builtin_bit_cast(f16x8, R##l[es][kc]);   \
                  acc[es] = __builtin_amdgcn_mfma_f32_16x16x32_f16(ah[kc], bh_, acc[es], 0, 0, 0); \
                  acc[es] = __builtin_amdgcn_mfma_f32_16x16x32_f16(ah[kc], bl_, acc[es], 0, 0, 0); \
                  acc[es] = __builtin_amdgcn_mfma_f32_16x16x32_f16(al[kc], bh_, acc[es], 0, 0, 0); \
              } }

    #define ROT() { int t_ = aCur; aCur = aNxt; aNxt = aStg; aStg = t_; }

    // prologue: tiles 0,1 in flight (A via gll, B via asm)
    STAGE_A(0, aCur)
    LOADB(0, b0)
    STAGE_A(1, aNxt)
    LOADB(1, b1)
    WAITV(10);                           // tile 0 (2 gll + 8 B) landed
    SB0();
    __builtin_amdgcn_s_barrier();

    // main loop: per iter issue 2 gll + 8 B-loads; WAITV(10) keeps tile i+2
    // in flight across the barrier (never drains to 0).
    for (int i = 0; i < NIT - 2; i += 2) {
        STAGE_A(i + 2, aStg)
        COMPUTE(aCur, b0)                // tile i (parity 0)
        LOADB(i + 2, b0)                 // overwrite parity-0 regs after use
        WAITV(10);
        SB0();
        __builtin_amdgcn_s_barrier();
        ROT();

        STAGE_A(i + 3, aStg)
        COMPUTE(aCur, b1)                // tile i+1 (parity 1)
        LOADB(i + 3, b1)
        WAITV(10);
        SB0();
        __builtin_amdgcn_s_barrier();
        ROT();
    }
    // tail: tiles 62, 63
    COMPUTE(aCur, b0)
    WAITV(0);
    SB0();
    __builtin_amdgcn_s_barrier();
    ROT();
    COMPUTE(aCur, b1)
    __builtin_amdgcn_s_barrier();        // all LDS reads done -> safe to alias

    // ---- fused epilogue ----
    #pragma unroll
    for (int es = 0; es < 2; ++es)
        #pragma unroll
        for (int r = 0; r < 4; ++r)
            sm.logits[wm * 16 + kg * 4 + r][we * 32 + es * 16 + l15]
                = acc[es][r] * INV_SCALE;
    __syncthreads();

    const size_t te = (size_t)T_ROWS * E_EXP;
    #pragma unroll
    for (int rr = 0; rr < 8; ++rr) {
        const int rl = wv * 8 + rr;
        const int gr = row0 + rl;
        const size_t idx = (size_t)gr * E_EXP + lane;
        const float val = sm.logits[rl][lane];

        out[2 * te + idx] = val;                      // logits_clean

        float m = val;
        #pragma unroll
        for (int off = 32; off; off >>= 1) m = fmaxf(m, __shfl_xor(m, off));
        const float p = expf(val - m);
        float ssum = p;
        #pragma unroll
        for (int off = 32; off; off >>= 1) ssum += __shfl_xor(ssum, off);
        out[1 * te + idx] = p / ssum;                 // probs

        const float uv = u[idx];
        const float g = -logf(-logf(uv));
        const float sel = val + g;
        out[3 * te + idx] = sel;                      // logits_sel

        // top-8, ties -> lowest lane (= lowest expert, matches lax.top_k)
        float v = sel;
        bool chosen = false;
        #pragma unroll
        for (int itk = 0; itk < TOPK; ++itk) {
            float mv = v;
            #pragma unroll
            for (int off = 32; off; off >>= 1) mv = fmaxf(mv, __shfl_xor(mv, off));
            const unsigned long long b = __ballot(v == mv);
            const int sl = __ffsll((long long)b) - 1;
            if (lane == sl) { chosen = true; v = -INFINITY; }
        }
        out[idx] = chosen ? 1.0f : 0.0f;              // mask
    }
}

// ---------------------------------------------------------------------------
extern "C" void kernel_launch(void* const* d_in, const int* in_sizes, int n_in,
                              void* d_out, int out_size, void* d_ws, size_t ws_size,
                              hipStream_t stream) {
    const float* h = (const float*)d_in[0];
    const float* W = (const float*)d_in[1];
    const float* u = (const float*)d_in[2];
    float* out = (float*)d_out;

    _Float16* Whi = (_Float16*)d_ws;                       // 512 KB
    _Float16* Wlo = Whi + (size_t)E_EXP * D_DIM;           // 512 KB

    hipLaunchKernelGGL(wprep_kernel, dim3(E_EXP * D_DIM / 8 / 256), dim3(256),
                       0, stream, W, Whi, Wlo);
    hipLaunchKernelGGL(router_main_kernel, dim3(T_ROWS / BM), dim3(256),
                       0, stream, h, Whi, Wlo, u, out);
}